// Round 7
// baseline (177.626 us; speedup 1.0000x reference)
//
#include <hip/hip_runtime.h>
#include <hip/hip_bf16.h>

#define B_ 2
#define T_ 2048
#define H_ 1024
#define NH 16
#define HD 64

typedef __attribute__((ext_vector_type(8))) short bf16x8;
typedef __attribute__((ext_vector_type(4))) short bf16x4;
typedef __attribute__((ext_vector_type(4))) float f32x4;

#define ASYNC_COPY16(gptr, lptr)                                              \
    __builtin_amdgcn_global_load_lds(                                         \
        (const __attribute__((address_space(1))) void*)(gptr),                \
        (__attribute__((address_space(3))) void*)(lptr), 16, 0, 0)

#if __has_builtin(__builtin_amdgcn_exp2f)
#define EXP2(x) __builtin_amdgcn_exp2f(x)
#else
static __device__ inline float EXP2(float x) {
    float r;
    asm volatile("v_exp_f32 %0, %1" : "=v"(r) : "v"(x));
    return r;
}
#endif

static __device__ inline unsigned short f2bf(float f) {
    union { float f; unsigned u; } v; v.f = f;
    unsigned r = v.u + 0x7fff + ((v.u >> 16) & 1);
    return (unsigned short)(r >> 16);
}

static __device__ inline unsigned pkbf(float a, float b) {
    float2 t2; t2.x = a; t2.y = b;
    __hip_bfloat162 h = __float22bfloat162_rn(t2);
    union { __hip_bfloat162 h; unsigned u; } cv; cv.h = h;
    return cv.u;
}

static __device__ inline bf16x8 mk8(unsigned a, unsigned b, unsigned c,
                                    unsigned d) {
    union { bf16x8 v; unsigned u[4]; } cv;
    cv.u[0] = a; cv.u[1] = b; cv.u[2] = c; cv.u[3] = d;
    return cv.v;
}

static __device__ inline f32x4 zero4() {
    f32x4 z = {0.f, 0.f, 0.f, 0.f};
    return z;
}

#define LOG2E 1.44269504088896f

// ---------------------------------------------------------------------------
// blocks 0..8191: fp32->bf16 of x|Wq|Wk|Wv|Wo
// block 8192: mask compaction scan  -> cidx / vidx / maskc / meta
// blocks 8193..12288: zero-fill of out (invalid rows must be 0; valid rows
// are overwritten by out_gemm later in the stream)
// ---------------------------------------------------------------------------
__global__ void cvt_kernel(const float* __restrict__ x,
                           const float* __restrict__ wq,
                           const float* __restrict__ wk,
                           const float* __restrict__ wv,
                           const float* __restrict__ wo,
                           const int* __restrict__ maskp,
                           unsigned short* __restrict__ dst,
                           unsigned* __restrict__ cidx,
                           unsigned short* __restrict__ vidx,
                           unsigned short* __restrict__ maskc,
                           unsigned* __restrict__ meta,
                           float* __restrict__ outz) {
    if (blockIdx.x > 8192) {
        long long idx =
            ((long long)(blockIdx.x - 8193) * 256 + threadIdx.x) * 4;
        if (idx < 4194304LL) {
            float4 z = {0.f, 0.f, 0.f, 0.f};
            *(float4*)(outz + idx) = z;
        }
        return;
    }
    if (blockIdx.x == 8192) {
        __shared__ unsigned ps[256];
        int t = threadIdx.x;
        int base = t * 16;
        int bb = base >> 11;
        unsigned mv = 0, cnt = 0;
#pragma unroll
        for (int i = 0; i < 16; i++) {
            if (maskp[base + i]) { mv |= (1u << i); cnt++; }
        }
        ps[t] = cnt;
        __syncthreads();
        for (int off = 1; off < 128; off <<= 1) {
            unsigned add = ((t & 127) >= off) ? ps[t - off] : 0;
            __syncthreads();
            ps[t] += add;
            __syncthreads();
        }
        unsigned cnt0 = ps[127], cnt1 = ps[255];
        unsigned ex = ps[t] - cnt;   // within-batch exclusive prefix
        unsigned local = ex;
        unsigned g = (bb ? cnt0 : 0) + ex;
        for (int i = 0; i < 16; i++) {
            if (mv & (1u << i)) {
                cidx[g] = (unsigned)(base + i);
                vidx[bb * 2048 + local] =
                    (unsigned short)(base + i - bb * 2048);
                maskc[bb * 2048 + local] = 0x3F80;
                g++; local++;
            }
        }
        if (t == 0) { meta[0] = cnt0; meta[1] = cnt1; meta[2] = cnt0 + cnt1; }
        __syncthreads();
        unsigned C = cnt0 + cnt1;
        for (unsigned i = C + t; i < 4224; i += 256) cidx[i] = 0;
        for (unsigned i = cnt0 + t; i < 2048; i += 256) {
            vidx[i] = 0; maskc[i] = 0;
        }
        for (unsigned i = cnt1 + t; i < 2048; i += 256) {
            vidx[2048 + i] = 0; maskc[2048 + i] = 0;
        }
        return;
    }
    long long i0 = ((long long)blockIdx.x * blockDim.x + threadIdx.x) * 4;
    const float* src; long long off;
    if (i0 < 4194304LL)      { src = x;  off = i0; }
    else if (i0 < 5242880LL) { src = wq; off = i0 - 4194304LL; }
    else if (i0 < 6291456LL) { src = wk; off = i0 - 5242880LL; }
    else if (i0 < 7340032LL) { src = wv; off = i0 - 6291456LL; }
    else                     { src = wo; off = i0 - 7340032LL; }
    float4 f = *(const float4*)(src + off);
    ushort4 o;
    o.x = f2bf(f.x); o.y = f2bf(f.y); o.z = f2bf(f.z); o.w = f2bf(f.w);
    *(ushort4*)(dst + i0) = o;
}

// ---------------------------------------------------------------------------
// QKV projection GEMM over COMPACTED rows, 64x128 (MxN) tiles.
// BK=128 SINGLE-buffer (48KB LDS = 3 blocks/CU, matching the active grid's
// 3/CU): 8 barrier-drain exposures (vs 16 at BK=64, 32 at BK=32) with
// 32 MFMA/wave of per-step cover. Continues the R5-validated fatter-step
// ladder (BK 32->64 was -5us); NOT the R6 dbuf (which halved TLP capacity).
// Four [rows][32] panels keep ds_read stride at 64B.
//   q: +bq, *0.125*log2e, [b,h,local,d];  k: +bk, [b,h,local,d]
//   v: +bv, TRANSPOSED [b,h,d,local]
// ---------------------------------------------------------------------------
__global__ __launch_bounds__(256) void qkv_gemm(
    const unsigned short* __restrict__ A,
    const unsigned short* __restrict__ Bm,
    const float* __restrict__ bq, const float* __restrict__ bk,
    const float* __restrict__ bv,
    const unsigned* __restrict__ cidx, const unsigned* __restrict__ meta,
    unsigned short* __restrict__ qout, unsigned short* __restrict__ kout,
    unsigned short* __restrict__ vout) {
    const int K = 1024;
    int C  = (int)meta[2];
    int c0 = (int)meta[0];
    int m0 = blockIdx.y * 64, n0 = blockIdx.x * 128;
    if (m0 >= C) return;
    __shared__ __align__(16) unsigned short As[4][64 * 32];
    __shared__ __align__(16) unsigned short Bs[4][128 * 32];
    int t = threadIdx.x;
    int w = t >> 6, lane = t & 63;
    int wm = (w >> 1) * 32, wn = (w & 1) * 64;
    int c = lane & 15, qd = lane >> 4;

    f32x4 acc[2][4];
#pragma unroll
    for (int i = 0; i < 2; i++)
#pragma unroll
        for (int j = 0; j < 4; j++) acc[i][j] = zero4();

    int srow = t >> 2, sseg = (t & 3) * 8;
    int r1 = (int)cidx[m0 + srow];
    const unsigned short* ag1 = A + (long long)r1 * K + sseg;
    const unsigned short* bg1 = Bm + (long long)(n0 + srow) * K + sseg;
    const unsigned short* bg2 = bg1 + 64LL * K;

    for (int kk = 0; kk < K; kk += 128) {
        __syncthreads();
#pragma unroll
        for (int p = 0; p < 4; p++) {
            ASYNC_COPY16(ag1 + kk + p * 32, &As[p][t * 8]);
            ASYNC_COPY16(bg1 + kk + p * 32, &Bs[p][t * 8]);
            ASYNC_COPY16(bg2 + kk + p * 32, &Bs[p][2048 + t * 8]);
        }
        __syncthreads();
#pragma unroll
        for (int p = 0; p < 4; p++) {
            bf16x8 af[2], bf[4];
#pragma unroll
            for (int i = 0; i < 2; i++)
                af[i] = *(const bf16x8*)(&As[p][(wm + i * 16 + c) * 32 +
                                                qd * 8]);
#pragma unroll
            for (int j = 0; j < 4; j++)
                bf[j] = *(const bf16x8*)(&Bs[p][(wn + j * 16 + c) * 32 +
                                                qd * 8]);
#pragma unroll
            for (int i = 0; i < 2; i++)
#pragma unroll
                for (int j = 0; j < 4; j++)
                    acc[i][j] = __builtin_amdgcn_mfma_f32_16x16x32_bf16(
                        af[i], bf[j], acc[i][j], 0, 0, 0);
        }
    }

    int gr[2][4];
#pragma unroll
    for (int i = 0; i < 2; i++)
#pragma unroll
        for (int r = 0; r < 4; r++) {
            int m = m0 + wm + i * 16 + qd * 4 + r;
            gr[i][r] = (m < C) ? (int)cidx[m] : -1;
        }

    const float QSCALE = 0.125f * LOG2E;
#pragma unroll
    for (int i = 0; i < 2; i++) {
        int m_base = m0 + wm + i * 16 + qd * 4;
#pragma unroll
        for (int j = 0; j < 4; j++) {
            int n = n0 + wn + j * 16 + c;
            int sel = n >> 10, within = n & 1023;
            int head = within >> 6, d = within & 63;
            if (sel == 0) {
                float ba = bq[within];
#pragma unroll
                for (int r = 0; r < 4; r++) {
                    if (gr[i][r] >= 0) {
                        int bb = gr[i][r] >> 11;
                        int loc = (m_base + r) - (bb ? c0 : 0);
                        qout[(((long long)(bb * NH + head)) * T_ + loc) * HD +
                             d] = f2bf((acc[i][j][r] + ba) * QSCALE);
                    }
                }
            } else if (sel == 1) {
                float ba = bk[within];
#pragma unroll
                for (int r = 0; r < 4; r++) {
                    if (gr[i][r] >= 0) {
                        int bb = gr[i][r] >> 11;
                        int loc = (m_base + r) - (bb ? c0 : 0);
                        kout[(((long long)(bb * NH + head)) * T_ + loc) * HD +
                             d] = f2bf(acc[i][j][r] + ba);
                    }
                }
            } else {
                float ba = bv[within];
                int g0 = gr[i][0], g3 = gr[i][3];
                int bb0 = g0 >> 11;
                int loc0 = m_base - (bb0 ? c0 : 0);
                if (g3 >= 0 && bb0 == (g3 >> 11) && ((loc0 & 3) == 0)) {
                    uint2 ov;
                    ov.x = pkbf(acc[i][j][0] + ba, acc[i][j][1] + ba);
                    ov.y = pkbf(acc[i][j][2] + ba, acc[i][j][3] + ba);
                    *(uint2*)(vout +
                              (((long long)(bb0 * NH + head)) * HD + d) * T_ +
                              loc0) = ov;
                } else {
#pragma unroll
                    for (int r = 0; r < 4; r++) {
                        if (gr[i][r] >= 0) {
                            int bb = gr[i][r] >> 11;
                            int loc = (m_base + r) - (bb ? c0 : 0);
                            vout[(((long long)(bb * NH + head)) * HD + d) *
                                     T_ +
                                 loc] = f2bf(acc[i][j][r] + ba);
                        }
                    }
                }
            }
        }
    }
}

// ---------------------------------------------------------------------------
// Output projection GEMM over COMPACTED rows, 64x64 tiles, BK=64
// single-buffer (16KB LDS, 16 steps — the R5-proven structure, unchanged).
// A rows gathered from hid via cidx; result scattered to true out rows
// (+bo). Invalid rows pre-zeroed.
// ---------------------------------------------------------------------------
__global__ __launch_bounds__(256) void out_gemm(
    const unsigned short* __restrict__ A,
    const unsigned short* __restrict__ Bm,
    const float* __restrict__ bo,
    const unsigned* __restrict__ cidx, const unsigned* __restrict__ meta,
    float* __restrict__ out) {
    const int K = 1024;
    int C = (int)meta[2];
    int m0 = blockIdx.y * 64, n0 = blockIdx.x * 64;
    if (m0 >= C) return;
    __shared__ __align__(16) unsigned short As[2][64 * 32];
    __shared__ __align__(16) unsigned short Bs[2][64 * 32];
    int t = threadIdx.x;
    int w = t >> 6, lane = t & 63;
    int wm = (w >> 1) * 32, wn = (w & 1) * 32;
    int c = lane & 15, qd = lane >> 4;

    f32x4 acc[2][2];
#pragma unroll
    for (int i = 0; i < 2; i++)
#pragma unroll
        for (int j = 0; j < 2; j++) acc[i][j] = zero4();

    int srow = t >> 2, sseg = (t & 3) * 8;
    int r1 = (int)cidx[m0 + srow];
    const unsigned short* ag1 = A + (long long)r1 * K + sseg;
    const unsigned short* bg1 = Bm + (long long)(n0 + srow) * K + sseg;

    for (int kk = 0; kk < K; kk += 64) {
        __syncthreads();
        ASYNC_COPY16(ag1 + kk,      &As[0][t * 8]);
        ASYNC_COPY16(ag1 + kk + 32, &As[1][t * 8]);
        ASYNC_COPY16(bg1 + kk,      &Bs[0][t * 8]);
        ASYNC_COPY16(bg1 + kk + 32, &Bs[1][t * 8]);
        __syncthreads();
#pragma unroll
        for (int p = 0; p < 2; p++) {
            bf16x8 af[2], bf[2];
#pragma unroll
            for (int i = 0; i < 2; i++)
                af[i] = *(const bf16x8*)(&As[p][(wm + i * 16 + c) * 32 +
                                                qd * 8]);
#pragma unroll
            for (int j = 0; j < 2; j++)
                bf[j] = *(const bf16x8*)(&Bs[p][(wn + j * 16 + c) * 32 +
                                                qd * 8]);
#pragma unroll
            for (int i = 0; i < 2; i++)
#pragma unroll
                for (int j = 0; j < 2; j++)
                    acc[i][j] = __builtin_amdgcn_mfma_f32_16x16x32_bf16(
                        af[i], bf[j], acc[i][j], 0, 0, 0);
        }
    }

#pragma unroll
    for (int i = 0; i < 2; i++) {
#pragma unroll
        for (int r = 0; r < 4; r++) {
            int m = m0 + wm + i * 16 + qd * 4 + r;
            if (m < C) {
                long long g = (long long)cidx[m];
#pragma unroll
                for (int j = 0; j < 2; j++) {
                    int n = n0 + wn + j * 16 + c;
                    out[g * 1024 + n] = acc[i][j][r] + bo[n];
                }
            }
        }
    }
}

// ---------------------------------------------------------------------------
// Attention v9 (unchanged, verified): QBLK=64, ~512 active blocks = 2/CU.
// Full-rate x32 PV via permuted K staging: LDS row i holds true key
// g(i) = (i&32) + ((i&15)>>2)*8 + ((i>>4)&1)*4 + (i&3), so QK output
// registers land in the 16x16x32 B-operand layout and PV/lacc run on the
// full-rate x32 MFMA with V/mask/kidx in TRUE order.
// ---------------------------------------------------------------------------
__global__ __launch_bounds__(256, 2) void attn_kernel(
    const unsigned short* __restrict__ qg,
    const unsigned short* __restrict__ kg,
    const unsigned short* __restrict__ vTg,
    const float* __restrict__ rel_bias,          // [9][16]
    const unsigned short* __restrict__ maskc,    // [B][2048] bf16 1/0
    const unsigned short* __restrict__ vidxg,    // [B][2048] u16 true t
    const unsigned* __restrict__ meta,
    unsigned short* __restrict__ hid) {          // [B*T][H] (true rows)
    int hb = blockIdx.x, qt = blockIdx.y;
    int h = hb & 15, b = hb >> 4;
    int cnt = (int)meta[b];
    if (qt * 64 >= cnt) return;
    int nkt = (cnt + 63) >> 6;
    int t = threadIdx.x, w = t >> 6, lane = t & 63;
    int c = lane & 15, qd = lane >> 4;

    __shared__ __align__(16) unsigned short lk[2][64 * 72];   // K (permuted rows)
    __shared__ __align__(16) unsigned short lvT[2][64 * 72];  // V^T[d][j] true order
    __shared__ __align__(16) unsigned short lmk[2][64];       // key valid bf16
    __shared__ __align__(16) unsigned short lki[2][64];       // key true pos
    __shared__ float lrbf[16];

    if (t < 9) lrbf[t] = rel_bias[t * 16 + h] * LOG2E;
    float rb0 = rel_bias[0 * 16 + h] * LOG2E;
    float rb8 = rel_bias[8 * 16 + h] * LOG2E;

    const unsigned short* qp =
        qg + (((long long)(b * NH + h)) * T_ + qt * 64) * HD;
    const unsigned short* kp = kg + ((long long)(b * NH + h)) * T_ * HD;
    const unsigned short* vp = vTg + ((long long)(b * NH + h)) * HD * T_;

    bf16x8 qf[2];
#pragma unroll
    for (int ks = 0; ks < 2; ks++)
        qf[ks] = *(const bf16x8*)(qp + (w * 16 + c) * HD + ks * 32 + qd * 8);

    const int imin = qt * 64 + w * 16;
    int imin_t = (int)vidxg[b * 2048 + min(imin, cnt - 1)];
    int imax_t = (int)vidxg[b * 2048 + min(imin + 15, cnt - 1)];
    int itrue = (int)vidxg[b * 2048 + min(imin + c, cnt - 1)];

    f32x4 o[4];
    f32x4 lacc;
#pragma unroll
    for (int dt = 0; dt < 4; dt++) o[dt] = zero4();
    lacc = zero4();

    int srow = t >> 2, sseg = (t & 3) * 16;
    int rr = srow & 15, hf = (srow >> 4) & 1;
    int gk = (srow & 32) + (rr >> 2) * 8 + hf * 4 + (rr & 3);  // permuted src row
    const unsigned short* kst = kp + gk * HD + sseg;
    const unsigned short* vst = vp + srow * T_ + sseg;
    const unsigned short* mst = maskc + b * 2048 + t;
    const unsigned short* ist = vidxg + b * 2048 + t * 8;

    uint4 rk0 = *(const uint4*)(kst);
    uint4 rk1 = *(const uint4*)(kst + 8);
    uint4 rv0 = *(const uint4*)(vst);
    uint4 rv1 = *(const uint4*)(vst + 8);
    unsigned short rm = (t < 64) ? *mst : 0;
    uint4 rki = {0, 0, 0, 0};
    if (t < 8) rki = *(const uint4*)(ist);

    for (int kt = 0; kt < nkt; kt++) {
        unsigned short* KB = lk[kt & 1];
        unsigned short* VB = lvT[kt & 1];
        unsigned short* MK = lmk[kt & 1];
        unsigned short* KI = lki[kt & 1];
        *(uint4*)(KB + srow * 72 + sseg)     = rk0;
        *(uint4*)(KB + srow * 72 + sseg + 8) = rk1;
        *(uint4*)(VB + srow * 72 + sseg)     = rv0;
        *(uint4*)(VB + srow * 72 + sseg + 8) = rv1;
        if (t < 64) MK[t] = rm;
        if (t < 8) *(uint4*)(KI + t * 8) = rki;
        {
            int ktn = (kt < nkt - 1) ? kt + 1 : nkt - 1;
            rk0 = *(const uint4*)(kst + ktn * 64 * HD);
            rk1 = *(const uint4*)(kst + ktn * 64 * HD + 8);
            rv0 = *(const uint4*)(vst + ktn * 64);
            rv1 = *(const uint4*)(vst + ktn * 64 + 8);
            if (t < 64) rm = mst[ktn * 64];
            if (t < 8) rki = *(const uint4*)(ist + ktn * 64);
        }
        __syncthreads();

        int j0 = kt * 64;
        int jlo_t = (int)KI[0];
        int jhi_t = (int)KI[min(63, cnt - 1 - j0)];
        bool far_lo = (jhi_t <= imin_t - 4);
        bool far_hi = (jlo_t >= imax_t + 4);
        float ub = far_lo ? rb0 : rb8;
        bool nearband = !(far_lo || far_hi);

#pragma unroll
        for (int jp = 0; jp < 2; jp++) {
            int jb = jp * 32;
            const unsigned short* kbase = KB + (jb + c) * 72 + qd * 8;
            bf16x8 kfA0 = *(const bf16x8*)(kbase);
            bf16x8 kfA1 = *(const bf16x8*)(kbase + 32);
            bf16x8 kfB0 = *(const bf16x8*)(kbase + 16 * 72);
            bf16x8 kfB1 = *(const bf16x8*)(kbase + 16 * 72 + 32);
            bf16x8 m8 = *(const bf16x8*)(MK + jb + qd * 8);
            ushort4 kivA = *(const ushort4*)(KI + jb + qd * 8);
            ushort4 kivB = *(const ushort4*)(KI + jb + qd * 8 + 4);
            bf16x8 vf[4];
#pragma unroll
            for (int dt = 0; dt < 4; dt++)
                vf[dt] = *(const bf16x8*)(VB + (dt * 16 + c) * 72 + jb +
                                          qd * 8);
            f32x4 accA = zero4(), accB = zero4();
            accA = __builtin_amdgcn_mfma_f32_16x16x32_bf16(kfA0, qf[0], accA,
                                                           0, 0, 0);
            accA = __builtin_amdgcn_mfma_f32_16x16x32_bf16(kfA1, qf[1], accA,
                                                           0, 0, 0);
            accB = __builtin_amdgcn_mfma_f32_16x16x32_bf16(kfB0, qf[0], accB,
                                                           0, 0, 0);
            accB = __builtin_amdgcn_mfma_f32_16x16x32_bf16(kfB1, qf[1], accB,
                                                           0, 0, 0);
            float pA0, pA1, pA2, pA3, pB0, pB1, pB2, pB3;
            if (nearband) {
                int it = itrue;
                int a0 = (int)kivA.x - it;
                a0 = a0 < -4 ? -4 : (a0 > 4 ? 4 : a0);
                int a1 = (int)kivA.y - it;
                a1 = a1 < -4 ? -4 : (a1 > 4 ? 4 : a1);
                int a2 = (int)kivA.z - it;
                a2 = a2 < -4 ? -4 : (a2 > 4 ? 4 : a2);
                int a3 = (int)kivA.w - it;
                a3 = a3 < -4 ? -4 : (a3 > 4 ? 4 : a3);
                int b0i = (int)kivB.x - it;
                b0i = b0i < -4 ? -4 : (b0i > 4 ? 4 : b0i);
                int b1i = (int)kivB.y - it;
                b1i = b1i < -4 ? -4 : (b1i > 4 ? 4 : b1i);
                int b2i = (int)kivB.z - it;
                b2i = b2i < -4 ? -4 : (b2i > 4 ? 4 : b2i);
                int b3i = (int)kivB.w - it;
                b3i = b3i < -4 ? -4 : (b3i > 4 ? 4 : b3i);
                pA0 = EXP2(accA[0] + lrbf[a0 + 4]);
                pA1 = EXP2(accA[1] + lrbf[a1 + 4]);
                pA2 = EXP2(accA[2] + lrbf[a2 + 4]);
                pA3 = EXP2(accA[3] + lrbf[a3 + 4]);
                pB0 = EXP2(accB[0] + lrbf[b0i + 4]);
                pB1 = EXP2(accB[1] + lrbf[b1i + 4]);
                pB2 = EXP2(accB[2] + lrbf[b2i + 4]);
                pB3 = EXP2(accB[3] + lrbf[b3i + 4]);
            } else {
                pA0 = EXP2(accA[0] + ub);
                pA1 = EXP2(accA[1] + ub);
                pA2 = EXP2(accA[2] + ub);
                pA3 = EXP2(accA[3] + ub);
                pB0 = EXP2(accB[0] + ub);
                pB1 = EXP2(accB[1] + ub);
                pB2 = EXP2(accB[2] + ub);
                pB3 = EXP2(accB[3] + ub);
            }
            bf16x8 pf = mk8(pkbf(pA0, pA1), pkbf(pA2, pA3),
                            pkbf(pB0, pB1), pkbf(pB2, pB3));
            lacc = __builtin_amdgcn_mfma_f32_16x16x32_bf16(m8, pf, lacc, 0,
                                                           0, 0);
#pragma unroll
            for (int dt = 0; dt < 4; dt++)
                o[dt] = __builtin_amdgcn_mfma_f32_16x16x32_bf16(
                    vf[dt], pf, o[dt], 0, 0, 0);
        }
    }

    // epilogue: normalize, scatter to TRUE rows; predicate on compact < cnt
    {
        int rc = imin + c;
        if (rc < cnt) {
            float invl = 1.0f / lacc[0];
            long long row = (long long)b * T_ + itrue;
#pragma unroll
            for (int dt = 0; dt < 4; dt++) {
                uint2 ov;
                ov.x = pkbf(o[dt][0] * invl, o[dt][1] * invl);
                ov.y = pkbf(o[dt][2] * invl, o[dt][3] * invl);
                *(uint2*)(hid + row * H_ + h * HD + dt * 16 + qd * 4) = ov;
            }
        }
    }
}

extern "C" void kernel_launch(void* const* d_in, const int* in_sizes, int n_in,
                              void* d_out, int out_size, void* d_ws,
                              size_t ws_size, hipStream_t stream) {
    const float* x    = (const float*)d_in[0];
    const int* maskp  = (const int*)d_in[1];
    const float* Wq   = (const float*)d_in[2];
    const float* bq   = (const float*)d_in[3];
    const float* Wk   = (const float*)d_in[4];
    const float* bk   = (const float*)d_in[5];
    const float* Wv   = (const float*)d_in[6];
    const float* bv   = (const float*)d_in[7];
    const float* Wo   = (const float*)d_in[8];
    const float* bo   = (const float*)d_in[9];
    const float* rb   = (const float*)d_in[10];
    float* out        = (float*)d_out;

    unsigned short* ws = (unsigned short*)d_ws;
    unsigned short* xb    = ws;                 // [0, 4M) elems
    unsigned short* wqkv  = ws + 4194304LL;     // [4M, 7M)
    unsigned short* wo_b  = ws + 7340032LL;     // [7M, 8M)
    unsigned short* qb    = ws + 8388608LL;     // [b,h,local,d]
    unsigned short* kb    = ws + 12582912LL;    // [b,h,local,d]
    unsigned short* vTb   = ws + 16777216LL;    // [b,h,d,local]
    unsigned short* hid   = ws + 20971520LL;    // [b*t][h*64+d] true rows
    unsigned* meta        = (unsigned*)(ws + 25165824LL);       // 4 u32
    unsigned* cidx        = (unsigned*)(ws + 25165856LL);       // 4224 u32
    unsigned short* vidx  = ws + 25174304LL;    // 4096 u16
    unsigned short* maskc = ws + 25178400LL;    // 4096 bf16

    cvt_kernel<<<12289, 256, 0, stream>>>(x, Wq, Wk, Wv, Wo, maskp, ws, cidx,
                                          vidx, maskc, meta, out);
    qkv_gemm<<<dim3(24, 64), 256, 0, stream>>>(xb, wqkv, bq, bk, bv, cidx,
                                               meta, qb, kb, vTb);
    attn_kernel<<<dim3(32, 32), 256, 0, stream>>>(qb, kb, vTb, rb, maskc,
                                                  vidx, meta, hid);
    out_gemm<<<dim3(16, 64), 256, 0, stream>>>(hid, wo_b, bo, cidx, meta,
                                               out);
}

// Round 8
// 167.161 us; speedup vs baseline: 1.0626x; 1.0626x over previous
//
#include <hip/hip_runtime.h>
#include <hip/hip_bf16.h>

#define B_ 2
#define T_ 2048
#define H_ 1024
#define NH 16
#define HD 64

typedef __attribute__((ext_vector_type(8))) short bf16x8;
typedef __attribute__((ext_vector_type(4))) short bf16x4;
typedef __attribute__((ext_vector_type(4))) float f32x4;

#define ASYNC_COPY16(gptr, lptr)                                              \
    __builtin_amdgcn_global_load_lds(                                         \
        (const __attribute__((address_space(1))) void*)(gptr),                \
        (__attribute__((address_space(3))) void*)(lptr), 16, 0, 0)

#if __has_builtin(__builtin_amdgcn_exp2f)
#define EXP2(x) __builtin_amdgcn_exp2f(x)
#else
static __device__ inline float EXP2(float x) {
    float r;
    asm volatile("v_exp_f32 %0, %1" : "=v"(r) : "v"(x));
    return r;
}
#endif

static __device__ inline unsigned short f2bf(float f) {
    union { float f; unsigned u; } v; v.f = f;
    unsigned r = v.u + 0x7fff + ((v.u >> 16) & 1);
    return (unsigned short)(r >> 16);
}

static __device__ inline unsigned pkbf(float a, float b) {
    float2 t2; t2.x = a; t2.y = b;
    __hip_bfloat162 h = __float22bfloat162_rn(t2);
    union { __hip_bfloat162 h; unsigned u; } cv; cv.h = h;
    return cv.u;
}

static __device__ inline bf16x8 mk8(unsigned a, unsigned b, unsigned c,
                                    unsigned d) {
    union { bf16x8 v; unsigned u[4]; } cv;
    cv.u[0] = a; cv.u[1] = b; cv.u[2] = c; cv.u[3] = d;
    return cv.v;
}

static __device__ inline f32x4 zero4() {
    f32x4 z = {0.f, 0.f, 0.f, 0.f};
    return z;
}

#define LOG2E 1.44269504088896f

// ---------------------------------------------------------------------------
// blocks 0..8191: fp32->bf16 of x|Wq|Wk|Wv|Wo
// block 8192: mask compaction scan  -> cidx / vidx / maskc / meta
// blocks 8193..12288: zero-fill of out (invalid rows must be 0; valid rows
// are overwritten by out_gemm later in the stream)
// At 143MB of unavoidable traffic this kernel runs at the 6.2 TB/s HBM
// ceiling (same rate as the harness fills) — at roofline.
// ---------------------------------------------------------------------------
__global__ void cvt_kernel(const float* __restrict__ x,
                           const float* __restrict__ wq,
                           const float* __restrict__ wk,
                           const float* __restrict__ wv,
                           const float* __restrict__ wo,
                           const int* __restrict__ maskp,
                           unsigned short* __restrict__ dst,
                           unsigned* __restrict__ cidx,
                           unsigned short* __restrict__ vidx,
                           unsigned short* __restrict__ maskc,
                           unsigned* __restrict__ meta,
                           float* __restrict__ outz) {
    if (blockIdx.x > 8192) {
        long long idx =
            ((long long)(blockIdx.x - 8193) * 256 + threadIdx.x) * 4;
        if (idx < 4194304LL) {
            float4 z = {0.f, 0.f, 0.f, 0.f};
            *(float4*)(outz + idx) = z;
        }
        return;
    }
    if (blockIdx.x == 8192) {
        __shared__ unsigned ps[256];
        int t = threadIdx.x;
        int base = t * 16;
        int bb = base >> 11;
        unsigned mv = 0, cnt = 0;
#pragma unroll
        for (int i = 0; i < 16; i++) {
            if (maskp[base + i]) { mv |= (1u << i); cnt++; }
        }
        ps[t] = cnt;
        __syncthreads();
        for (int off = 1; off < 128; off <<= 1) {
            unsigned add = ((t & 127) >= off) ? ps[t - off] : 0;
            __syncthreads();
            ps[t] += add;
            __syncthreads();
        }
        unsigned cnt0 = ps[127], cnt1 = ps[255];
        unsigned ex = ps[t] - cnt;   // within-batch exclusive prefix
        unsigned local = ex;
        unsigned g = (bb ? cnt0 : 0) + ex;
        for (int i = 0; i < 16; i++) {
            if (mv & (1u << i)) {
                cidx[g] = (unsigned)(base + i);
                vidx[bb * 2048 + local] =
                    (unsigned short)(base + i - bb * 2048);
                maskc[bb * 2048 + local] = 0x3F80;
                g++; local++;
            }
        }
        if (t == 0) { meta[0] = cnt0; meta[1] = cnt1; meta[2] = cnt0 + cnt1; }
        __syncthreads();
        unsigned C = cnt0 + cnt1;
        for (unsigned i = C + t; i < 4224; i += 256) cidx[i] = 0;
        for (unsigned i = cnt0 + t; i < 2048; i += 256) {
            vidx[i] = 0; maskc[i] = 0;
        }
        for (unsigned i = cnt1 + t; i < 2048; i += 256) {
            vidx[2048 + i] = 0; maskc[2048 + i] = 0;
        }
        return;
    }
    long long i0 = ((long long)blockIdx.x * blockDim.x + threadIdx.x) * 4;
    const float* src; long long off;
    if (i0 < 4194304LL)      { src = x;  off = i0; }
    else if (i0 < 5242880LL) { src = wq; off = i0 - 4194304LL; }
    else if (i0 < 6291456LL) { src = wk; off = i0 - 5242880LL; }
    else if (i0 < 7340032LL) { src = wv; off = i0 - 6291456LL; }
    else                     { src = wo; off = i0 - 7340032LL; }
    float4 f = *(const float4*)(src + off);
    ushort4 o;
    o.x = f2bf(f.x); o.y = f2bf(f.y); o.z = f2bf(f.z); o.w = f2bf(f.w);
    *(ushort4*)(dst + i0) = o;
}

// ---------------------------------------------------------------------------
// QKV projection GEMM over COMPACTED rows, 64x128 (MxN) tiles.
// BK=64 SINGLE-buffer (24KB LDS): the measured optimum of the fatter-step
// ladder (BK=32: 42us, BK=64: ~37us, BK=128: regressed to +8us total via
// the 3-blocks/CU occupancy squeeze; dbuf variants R2/R6 both regressed).
// Two [rows][32] panels keep ds_read stride at 64B.
//   q: +bq, *0.125*log2e, [b,h,local,d];  k: +bk, [b,h,local,d]
//   v: +bv, TRANSPOSED [b,h,d,local]
// ---------------------------------------------------------------------------
__global__ __launch_bounds__(256) void qkv_gemm(
    const unsigned short* __restrict__ A,
    const unsigned short* __restrict__ Bm,
    const float* __restrict__ bq, const float* __restrict__ bk,
    const float* __restrict__ bv,
    const unsigned* __restrict__ cidx, const unsigned* __restrict__ meta,
    unsigned short* __restrict__ qout, unsigned short* __restrict__ kout,
    unsigned short* __restrict__ vout) {
    const int K = 1024;
    int C  = (int)meta[2];
    int c0 = (int)meta[0];
    int m0 = blockIdx.y * 64, n0 = blockIdx.x * 128;
    if (m0 >= C) return;
    __shared__ __align__(16) unsigned short As[2][64 * 32];
    __shared__ __align__(16) unsigned short Bs[2][128 * 32];
    int t = threadIdx.x;
    int w = t >> 6, lane = t & 63;
    int wm = (w >> 1) * 32, wn = (w & 1) * 64;
    int c = lane & 15, qd = lane >> 4;

    f32x4 acc[2][4];
#pragma unroll
    for (int i = 0; i < 2; i++)
#pragma unroll
        for (int j = 0; j < 4; j++) acc[i][j] = zero4();

    int srow = t >> 2, sseg = (t & 3) * 8;
    int r1 = (int)cidx[m0 + srow];
    const unsigned short* ag1 = A + (long long)r1 * K + sseg;
    const unsigned short* bg1 = Bm + (long long)(n0 + srow) * K + sseg;
    const unsigned short* bg2 = bg1 + 64LL * K;

    for (int kk = 0; kk < K; kk += 64) {
        __syncthreads();
        ASYNC_COPY16(ag1 + kk,      &As[0][t * 8]);
        ASYNC_COPY16(ag1 + kk + 32, &As[1][t * 8]);
        ASYNC_COPY16(bg1 + kk,      &Bs[0][t * 8]);
        ASYNC_COPY16(bg1 + kk + 32, &Bs[1][t * 8]);
        ASYNC_COPY16(bg2 + kk,      &Bs[0][2048 + t * 8]);
        ASYNC_COPY16(bg2 + kk + 32, &Bs[1][2048 + t * 8]);
        __syncthreads();
#pragma unroll
        for (int p = 0; p < 2; p++) {
            bf16x8 af[2], bf[4];
#pragma unroll
            for (int i = 0; i < 2; i++)
                af[i] = *(const bf16x8*)(&As[p][(wm + i * 16 + c) * 32 +
                                                qd * 8]);
#pragma unroll
            for (int j = 0; j < 4; j++)
                bf[j] = *(const bf16x8*)(&Bs[p][(wn + j * 16 + c) * 32 +
                                                qd * 8]);
#pragma unroll
            for (int i = 0; i < 2; i++)
#pragma unroll
                for (int j = 0; j < 4; j++)
                    acc[i][j] = __builtin_amdgcn_mfma_f32_16x16x32_bf16(
                        af[i], bf[j], acc[i][j], 0, 0, 0);
        }
    }

    int gr[2][4];
#pragma unroll
    for (int i = 0; i < 2; i++)
#pragma unroll
        for (int r = 0; r < 4; r++) {
            int m = m0 + wm + i * 16 + qd * 4 + r;
            gr[i][r] = (m < C) ? (int)cidx[m] : -1;
        }

    const float QSCALE = 0.125f * LOG2E;
#pragma unroll
    for (int i = 0; i < 2; i++) {
        int m_base = m0 + wm + i * 16 + qd * 4;
#pragma unroll
        for (int j = 0; j < 4; j++) {
            int n = n0 + wn + j * 16 + c;
            int sel = n >> 10, within = n & 1023;
            int head = within >> 6, d = within & 63;
            if (sel == 0) {
                float ba = bq[within];
#pragma unroll
                for (int r = 0; r < 4; r++) {
                    if (gr[i][r] >= 0) {
                        int bb = gr[i][r] >> 11;
                        int loc = (m_base + r) - (bb ? c0 : 0);
                        qout[(((long long)(bb * NH + head)) * T_ + loc) * HD +
                             d] = f2bf((acc[i][j][r] + ba) * QSCALE);
                    }
                }
            } else if (sel == 1) {
                float ba = bk[within];
#pragma unroll
                for (int r = 0; r < 4; r++) {
                    if (gr[i][r] >= 0) {
                        int bb = gr[i][r] >> 11;
                        int loc = (m_base + r) - (bb ? c0 : 0);
                        kout[(((long long)(bb * NH + head)) * T_ + loc) * HD +
                             d] = f2bf(acc[i][j][r] + ba);
                    }
                }
            } else {
                float ba = bv[within];
                int g0 = gr[i][0], g3 = gr[i][3];
                int bb0 = g0 >> 11;
                int loc0 = m_base - (bb0 ? c0 : 0);
                if (g3 >= 0 && bb0 == (g3 >> 11) && ((loc0 & 3) == 0)) {
                    uint2 ov;
                    ov.x = pkbf(acc[i][j][0] + ba, acc[i][j][1] + ba);
                    ov.y = pkbf(acc[i][j][2] + ba, acc[i][j][3] + ba);
                    *(uint2*)(vout +
                              (((long long)(bb0 * NH + head)) * HD + d) * T_ +
                              loc0) = ov;
                } else {
#pragma unroll
                    for (int r = 0; r < 4; r++) {
                        if (gr[i][r] >= 0) {
                            int bb = gr[i][r] >> 11;
                            int loc = (m_base + r) - (bb ? c0 : 0);
                            vout[(((long long)(bb * NH + head)) * HD + d) *
                                     T_ +
                                 loc] = f2bf(acc[i][j][r] + ba);
                        }
                    }
                }
            }
        }
    }
}

// ---------------------------------------------------------------------------
// Output projection GEMM over COMPACTED rows, 64x64 tiles, BK=64
// single-buffer (16KB LDS, 16 steps — the R5-proven structure).
// A rows gathered from hid via cidx; result scattered to true out rows
// (+bo). Invalid rows pre-zeroed.
// ---------------------------------------------------------------------------
__global__ __launch_bounds__(256) void out_gemm(
    const unsigned short* __restrict__ A,
    const unsigned short* __restrict__ Bm,
    const float* __restrict__ bo,
    const unsigned* __restrict__ cidx, const unsigned* __restrict__ meta,
    float* __restrict__ out) {
    const int K = 1024;
    int C = (int)meta[2];
    int m0 = blockIdx.y * 64, n0 = blockIdx.x * 64;
    if (m0 >= C) return;
    __shared__ __align__(16) unsigned short As[2][64 * 32];
    __shared__ __align__(16) unsigned short Bs[2][64 * 32];
    int t = threadIdx.x;
    int w = t >> 6, lane = t & 63;
    int wm = (w >> 1) * 32, wn = (w & 1) * 32;
    int c = lane & 15, qd = lane >> 4;

    f32x4 acc[2][2];
#pragma unroll
    for (int i = 0; i < 2; i++)
#pragma unroll
        for (int j = 0; j < 2; j++) acc[i][j] = zero4();

    int srow = t >> 2, sseg = (t & 3) * 8;
    int r1 = (int)cidx[m0 + srow];
    const unsigned short* ag1 = A + (long long)r1 * K + sseg;
    const unsigned short* bg1 = Bm + (long long)(n0 + srow) * K + sseg;

    for (int kk = 0; kk < K; kk += 64) {
        __syncthreads();
        ASYNC_COPY16(ag1 + kk,      &As[0][t * 8]);
        ASYNC_COPY16(ag1 + kk + 32, &As[1][t * 8]);
        ASYNC_COPY16(bg1 + kk,      &Bs[0][t * 8]);
        ASYNC_COPY16(bg1 + kk + 32, &Bs[1][t * 8]);
        __syncthreads();
#pragma unroll
        for (int p = 0; p < 2; p++) {
            bf16x8 af[2], bf[2];
#pragma unroll
            for (int i = 0; i < 2; i++)
                af[i] = *(const bf16x8*)(&As[p][(wm + i * 16 + c) * 32 +
                                                qd * 8]);
#pragma unroll
            for (int j = 0; j < 2; j++)
                bf[j] = *(const bf16x8*)(&Bs[p][(wn + j * 16 + c) * 32 +
                                                qd * 8]);
#pragma unroll
            for (int i = 0; i < 2; i++)
#pragma unroll
                for (int j = 0; j < 2; j++)
                    acc[i][j] = __builtin_amdgcn_mfma_f32_16x16x32_bf16(
                        af[i], bf[j], acc[i][j], 0, 0, 0);
        }
    }

#pragma unroll
    for (int i = 0; i < 2; i++) {
#pragma unroll
        for (int r = 0; r < 4; r++) {
            int m = m0 + wm + i * 16 + qd * 4 + r;
            if (m < C) {
                long long g = (long long)cidx[m];
#pragma unroll
                for (int j = 0; j < 2; j++) {
                    int n = n0 + wn + j * 16 + c;
                    out[g * 1024 + n] = acc[i][j][r] + bo[n];
                }
            }
        }
    }
}

// ---------------------------------------------------------------------------
// Attention v9 (verified): QBLK=64, ~512 active blocks = 2/CU.
// Full-rate x32 PV via permuted K staging: LDS row i holds true key
// g(i) = (i&32) + ((i&15)>>2)*8 + ((i>>4)&1)*4 + (i&3), so QK output
// registers land in the 16x16x32 B-operand layout and PV/lacc run on the
// full-rate x32 MFMA with V/mask/kidx in TRUE order.
// ---------------------------------------------------------------------------
__global__ __launch_bounds__(256, 2) void attn_kernel(
    const unsigned short* __restrict__ qg,
    const unsigned short* __restrict__ kg,
    const unsigned short* __restrict__ vTg,
    const float* __restrict__ rel_bias,          // [9][16]
    const unsigned short* __restrict__ maskc,    // [B][2048] bf16 1/0
    const unsigned short* __restrict__ vidxg,    // [B][2048] u16 true t
    const unsigned* __restrict__ meta,
    unsigned short* __restrict__ hid) {          // [B*T][H] (true rows)
    int hb = blockIdx.x, qt = blockIdx.y;
    int h = hb & 15, b = hb >> 4;
    int cnt = (int)meta[b];
    if (qt * 64 >= cnt) return;
    int nkt = (cnt + 63) >> 6;
    int t = threadIdx.x, w = t >> 6, lane = t & 63;
    int c = lane & 15, qd = lane >> 4;

    __shared__ __align__(16) unsigned short lk[2][64 * 72];   // K (permuted rows)
    __shared__ __align__(16) unsigned short lvT[2][64 * 72];  // V^T[d][j] true order
    __shared__ __align__(16) unsigned short lmk[2][64];       // key valid bf16
    __shared__ __align__(16) unsigned short lki[2][64];       // key true pos
    __shared__ float lrbf[16];

    if (t < 9) lrbf[t] = rel_bias[t * 16 + h] * LOG2E;
    float rb0 = rel_bias[0 * 16 + h] * LOG2E;
    float rb8 = rel_bias[8 * 16 + h] * LOG2E;

    const unsigned short* qp =
        qg + (((long long)(b * NH + h)) * T_ + qt * 64) * HD;
    const unsigned short* kp = kg + ((long long)(b * NH + h)) * T_ * HD;
    const unsigned short* vp = vTg + ((long long)(b * NH + h)) * HD * T_;

    bf16x8 qf[2];
#pragma unroll
    for (int ks = 0; ks < 2; ks++)
        qf[ks] = *(const bf16x8*)(qp + (w * 16 + c) * HD + ks * 32 + qd * 8);

    const int imin = qt * 64 + w * 16;
    int imin_t = (int)vidxg[b * 2048 + min(imin, cnt - 1)];
    int imax_t = (int)vidxg[b * 2048 + min(imin + 15, cnt - 1)];
    int itrue = (int)vidxg[b * 2048 + min(imin + c, cnt - 1)];

    f32x4 o[4];
    f32x4 lacc;
#pragma unroll
    for (int dt = 0; dt < 4; dt++) o[dt] = zero4();
    lacc = zero4();

    int srow = t >> 2, sseg = (t & 3) * 16;
    int rr = srow & 15, hf = (srow >> 4) & 1;
    int gk = (srow & 32) + (rr >> 2) * 8 + hf * 4 + (rr & 3);  // permuted src row
    const unsigned short* kst = kp + gk * HD + sseg;
    const unsigned short* vst = vp + srow * T_ + sseg;
    const unsigned short* mst = maskc + b * 2048 + t;
    const unsigned short* ist = vidxg + b * 2048 + t * 8;

    uint4 rk0 = *(const uint4*)(kst);
    uint4 rk1 = *(const uint4*)(kst + 8);
    uint4 rv0 = *(const uint4*)(vst);
    uint4 rv1 = *(const uint4*)(vst + 8);
    unsigned short rm = (t < 64) ? *mst : 0;
    uint4 rki = {0, 0, 0, 0};
    if (t < 8) rki = *(const uint4*)(ist);

    for (int kt = 0; kt < nkt; kt++) {
        unsigned short* KB = lk[kt & 1];
        unsigned short* VB = lvT[kt & 1];
        unsigned short* MK = lmk[kt & 1];
        unsigned short* KI = lki[kt & 1];
        *(uint4*)(KB + srow * 72 + sseg)     = rk0;
        *(uint4*)(KB + srow * 72 + sseg + 8) = rk1;
        *(uint4*)(VB + srow * 72 + sseg)     = rv0;
        *(uint4*)(VB + srow * 72 + sseg + 8) = rv1;
        if (t < 64) MK[t] = rm;
        if (t < 8) *(uint4*)(KI + t * 8) = rki;
        {
            int ktn = (kt < nkt - 1) ? kt + 1 : nkt - 1;
            rk0 = *(const uint4*)(kst + ktn * 64 * HD);
            rk1 = *(const uint4*)(kst + ktn * 64 * HD + 8);
            rv0 = *(const uint4*)(vst + ktn * 64);
            rv1 = *(const uint4*)(vst + ktn * 64 + 8);
            if (t < 64) rm = mst[ktn * 64];
            if (t < 8) rki = *(const uint4*)(ist + ktn * 64);
        }
        __syncthreads();

        int j0 = kt * 64;
        int jlo_t = (int)KI[0];
        int jhi_t = (int)KI[min(63, cnt - 1 - j0)];
        bool far_lo = (jhi_t <= imin_t - 4);
        bool far_hi = (jlo_t >= imax_t + 4);
        float ub = far_lo ? rb0 : rb8;
        bool nearband = !(far_lo || far_hi);

#pragma unroll
        for (int jp = 0; jp < 2; jp++) {
            int jb = jp * 32;
            const unsigned short* kbase = KB + (jb + c) * 72 + qd * 8;
            bf16x8 kfA0 = *(const bf16x8*)(kbase);
            bf16x8 kfA1 = *(const bf16x8*)(kbase + 32);
            bf16x8 kfB0 = *(const bf16x8*)(kbase + 16 * 72);
            bf16x8 kfB1 = *(const bf16x8*)(kbase + 16 * 72 + 32);
            bf16x8 m8 = *(const bf16x8*)(MK + jb + qd * 8);
            ushort4 kivA = *(const ushort4*)(KI + jb + qd * 8);
            ushort4 kivB = *(const ushort4*)(KI + jb + qd * 8 + 4);
            bf16x8 vf[4];
#pragma unroll
            for (int dt = 0; dt < 4; dt++)
                vf[dt] = *(const bf16x8*)(VB + (dt * 16 + c) * 72 + jb +
                                          qd * 8);
            f32x4 accA = zero4(), accB = zero4();
            accA = __builtin_amdgcn_mfma_f32_16x16x32_bf16(kfA0, qf[0], accA,
                                                           0, 0, 0);
            accA = __builtin_amdgcn_mfma_f32_16x16x32_bf16(kfA1, qf[1], accA,
                                                           0, 0, 0);
            accB = __builtin_amdgcn_mfma_f32_16x16x32_bf16(kfB0, qf[0], accB,
                                                           0, 0, 0);
            accB = __builtin_amdgcn_mfma_f32_16x16x32_bf16(kfB1, qf[1], accB,
                                                           0, 0, 0);
            float pA0, pA1, pA2, pA3, pB0, pB1, pB2, pB3;
            if (nearband) {
                int it = itrue;
                int a0 = (int)kivA.x - it;
                a0 = a0 < -4 ? -4 : (a0 > 4 ? 4 : a0);
                int a1 = (int)kivA.y - it;
                a1 = a1 < -4 ? -4 : (a1 > 4 ? 4 : a1);
                int a2 = (int)kivA.z - it;
                a2 = a2 < -4 ? -4 : (a2 > 4 ? 4 : a2);
                int a3 = (int)kivA.w - it;
                a3 = a3 < -4 ? -4 : (a3 > 4 ? 4 : a3);
                int b0i = (int)kivB.x - it;
                b0i = b0i < -4 ? -4 : (b0i > 4 ? 4 : b0i);
                int b1i = (int)kivB.y - it;
                b1i = b1i < -4 ? -4 : (b1i > 4 ? 4 : b1i);
                int b2i = (int)kivB.z - it;
                b2i = b2i < -4 ? -4 : (b2i > 4 ? 4 : b2i);
                int b3i = (int)kivB.w - it;
                b3i = b3i < -4 ? -4 : (b3i > 4 ? 4 : b3i);
                pA0 = EXP2(accA[0] + lrbf[a0 + 4]);
                pA1 = EXP2(accA[1] + lrbf[a1 + 4]);
                pA2 = EXP2(accA[2] + lrbf[a2 + 4]);
                pA3 = EXP2(accA[3] + lrbf[a3 + 4]);
                pB0 = EXP2(accB[0] + lrbf[b0i + 4]);
                pB1 = EXP2(accB[1] + lrbf[b1i + 4]);
                pB2 = EXP2(accB[2] + lrbf[b2i + 4]);
                pB3 = EXP2(accB[3] + lrbf[b3i + 4]);
            } else {
                pA0 = EXP2(accA[0] + ub);
                pA1 = EXP2(accA[1] + ub);
                pA2 = EXP2(accA[2] + ub);
                pA3 = EXP2(accA[3] + ub);
                pB0 = EXP2(accB[0] + ub);
                pB1 = EXP2(accB[1] + ub);
                pB2 = EXP2(accB[2] + ub);
                pB3 = EXP2(accB[3] + ub);
            }
            bf16x8 pf = mk8(pkbf(pA0, pA1), pkbf(pA2, pA3),
                            pkbf(pB0, pB1), pkbf(pB2, pB3));
            lacc = __builtin_amdgcn_mfma_f32_16x16x32_bf16(m8, pf, lacc, 0,
                                                           0, 0);
#pragma unroll
            for (int dt = 0; dt < 4; dt++)
                o[dt] = __builtin_amdgcn_mfma_f32_16x16x32_bf16(
                    vf[dt], pf, o[dt], 0, 0, 0);
        }
    }

    // epilogue: normalize, scatter to TRUE rows; predicate on compact < cnt
    {
        int rc = imin + c;
        if (rc < cnt) {
            float invl = 1.0f / lacc[0];
            long long row = (long long)b * T_ + itrue;
#pragma unroll
            for (int dt = 0; dt < 4; dt++) {
                uint2 ov;
                ov.x = pkbf(o[dt][0] * invl, o[dt][1] * invl);
                ov.y = pkbf(o[dt][2] * invl, o[dt][3] * invl);
                *(uint2*)(hid + row * H_ + h * HD + dt * 16 + qd * 4) = ov;
            }
        }
    }
}

extern "C" void kernel_launch(void* const* d_in, const int* in_sizes, int n_in,
                              void* d_out, int out_size, void* d_ws,
                              size_t ws_size, hipStream_t stream) {
    const float* x    = (const float*)d_in[0];
    const int* maskp  = (const int*)d_in[1];
    const float* Wq   = (const float*)d_in[2];
    const float* bq   = (const float*)d_in[3];
    const float* Wk   = (const float*)d_in[4];
    const float* bk   = (const float*)d_in[5];
    const float* Wv   = (const float*)d_in[6];
    const float* bv   = (const float*)d_in[7];
    const float* Wo   = (const float*)d_in[8];
    const float* bo   = (const float*)d_in[9];
    const float* rb   = (const float*)d_in[10];
    float* out        = (float*)d_out;

    unsigned short* ws = (unsigned short*)d_ws;
    unsigned short* xb    = ws;                 // [0, 4M) elems
    unsigned short* wqkv  = ws + 4194304LL;     // [4M, 7M)
    unsigned short* wo_b  = ws + 7340032LL;     // [7M, 8M)
    unsigned short* qb    = ws + 8388608LL;     // [b,h,local,d]
    unsigned short* kb    = ws + 12582912LL;    // [b,h,local,d]
    unsigned short* vTb   = ws + 16777216LL;    // [b,h,d,local]
    unsigned short* hid   = ws + 20971520LL;    // [b*t][h*64+d] true rows
    unsigned* meta        = (unsigned*)(ws + 25165824LL);       // 4 u32
    unsigned* cidx        = (unsigned*)(ws + 25165856LL);       // 4224 u32
    unsigned short* vidx  = ws + 25174304LL;    // 4096 u16
    unsigned short* maskc = ws + 25178400LL;    // 4096 bf16

    cvt_kernel<<<12289, 256, 0, stream>>>(x, Wq, Wk, Wv, Wo, maskp, ws, cidx,
                                          vidx, maskc, meta, out);
    qkv_gemm<<<dim3(24, 64), 256, 0, stream>>>(xb, wqkv, bq, bk, bv, cidx,
                                               meta, qb, kb, vTb);
    attn_kernel<<<dim3(32, 32), 256, 0, stream>>>(qb, kb, vTb, rb, maskc,
                                                  vidx, meta, hid);
    out_gemm<<<dim3(16, 64), 256, 0, stream>>>(hid, wo_b, bo, cidx, meta,
                                               out);
}